// Round 4
// baseline (548.215 us; speedup 1.0000x reference)
//
#include <hip/hip_runtime.h>

// Problem constants: B=16, TQ=256, TK=256, QD=512, KD=512
// d_out = [ tanh_out: 16*256*512 f32 ; p: 16*256*256 f32 ]
// scores[b,q,k] = (sum_n w_n + b_att) - 2 * sum_n w_n / (1 + Ea[q,n]*Ek[k,n])
//   Ea = exp2(C2*aq), Ek = exp2(C2*keys), C2 = 2*log2(e)
// Pairwise: w1/q1 + w2/q2 = (w1*q2 + w2*q1) / (q1*q2),  q = 1 + Ea*Ek

#define C2 2.88539008177792681f

typedef unsigned short u16;
typedef short s16x8 __attribute__((ext_vector_type(8)));
typedef float f32x4 __attribute__((ext_vector_type(4)));

__device__ __forceinline__ float fast_rcp(float x) { return __builtin_amdgcn_rcpf(x); }

__device__ __forceinline__ u16 f2bf(float f) {
  union { float f; unsigned u; } v; v.f = f;
  unsigned r = v.u + 0x7fffu + ((v.u >> 16) & 1u);
  return (u16)(r >> 16);
}
__device__ __forceinline__ unsigned packbf(float a, float b) {
  return (unsigned)f2bf(a) | ((unsigned)f2bf(b) << 16);
}

// ---------------------------------------------------------------------------
// Prep: Wt[n][k] = bf16(W[k][n]);  W is [K][512] f32, Wt is [512][K] bf16.
// ---------------------------------------------------------------------------
__global__ __launch_bounds__(256) void transpose_w_bf16(
    const float* __restrict__ W, u16* __restrict__ Wt, int K)
{
  __shared__ u16 tile[32][40];
  const int t = threadIdx.x;
  const int n0 = blockIdx.x * 32, k0 = blockIdx.y * 32;
  const int r = t >> 3, c = (t & 7) * 4;
  float4 v = *(const float4*)&W[(size_t)(k0 + r) * 512 + n0 + c];
  tile[c + 0][r] = f2bf(v.x); tile[c + 1][r] = f2bf(v.y);
  tile[c + 2][r] = f2bf(v.z); tile[c + 3][r] = f2bf(v.w);
  __syncthreads();
  if (t < 128) {
    const int row = t >> 2, ch = (t & 3) * 8;
    unsigned p0 = (unsigned)tile[row][ch + 0] | ((unsigned)tile[row][ch + 1] << 16);
    unsigned p1 = (unsigned)tile[row][ch + 2] | ((unsigned)tile[row][ch + 3] << 16);
    unsigned p2 = (unsigned)tile[row][ch + 4] | ((unsigned)tile[row][ch + 5] << 16);
    unsigned p3 = (unsigned)tile[row][ch + 6] | ((unsigned)tile[row][ch + 7] << 16);
    *(int4*)&Wt[(size_t)(n0 + row) * K + k0 + ch] = make_int4(p0, p1, p2, p3);
  }
}

// ---------------------------------------------------------------------------
// K1/K4: bf16 MFMA GEMM. C[M][512] = act(A @ W + bias), A fp32 -> bf16 staged.
// Tile 64(M) x 64(N), BK=32, 4 waves (2x2), wave tile 32x32 (2x2 frags).
// ---------------------------------------------------------------------------
__global__ __launch_bounds__(256) void gemm_mfma_bf16(
    const float* __restrict__ A0, const float* __restrict__ A1, int kSplit,
    const u16* __restrict__ Bt, const float* __restrict__ bias,
    float* __restrict__ C, int K, int act)
{
  __shared__ u16 As[64 * 32];  // [row][k]
  __shared__ u16 Bs[64 * 32];  // [col][k]
  const int t = threadIdx.x;
  const int lane = t & 63, wid = t >> 6;
  const int wm = wid >> 1, wn = wid & 1;
  const int col0 = blockIdx.x * 64, row0 = blockIdx.y * 64;

  const int ar = t >> 2, ah = (t & 3) * 8;  // A staging: row, 8-elem chunk
  const int br = t >> 2, bc = (t & 3) * 8;  // B staging: col, 8-elem chunk
  const int fr = lane & 15, fg = (lane >> 4) * 8;

  f32x4 acc[2][2] = {};

  for (int k0 = 0; k0 < K; k0 += 32) {
    const float* Asrc; int kc;
    if (k0 < kSplit) { Asrc = A0; kc = k0; } else { Asrc = A1; kc = k0 - kSplit; }
    const float* ap = &Asrc[(size_t)(row0 + ar) * 512 + kc + ah];
    float4 av0 = *(const float4*)(ap + 0);
    float4 av1 = *(const float4*)(ap + 4);
    int4 bv = *(const int4*)&Bt[(size_t)(col0 + br) * K + k0 + bc];
    __syncthreads();
    {
      unsigned p0 = packbf(av0.x, av0.y), p1 = packbf(av0.z, av0.w);
      unsigned p2 = packbf(av1.x, av1.y), p3 = packbf(av1.z, av1.w);
      *(int4*)&As[ar * 32 + ah] = make_int4(p0, p1, p2, p3);
      *(int4*)&Bs[br * 32 + bc] = bv;
    }
    __syncthreads();

    s16x8 af[2], bf[2];
#pragma unroll
    for (int m = 0; m < 2; ++m)
      af[m] = *(const s16x8*)&As[(wm * 32 + m * 16 + fr) * 32 + fg];
#pragma unroll
    for (int n = 0; n < 2; ++n)
      bf[n] = *(const s16x8*)&Bs[(wn * 32 + n * 16 + fr) * 32 + fg];
#pragma unroll
    for (int m = 0; m < 2; ++m)
#pragma unroll
      for (int n = 0; n < 2; ++n)
        acc[m][n] = __builtin_amdgcn_mfma_f32_16x16x32_bf16(af[m], bf[n], acc[m][n], 0, 0, 0);
  }

  const int fq = lane >> 4;
#pragma unroll
  for (int n = 0; n < 2; ++n) {
    const int col = col0 + wn * 32 + n * 16 + fr;
    const float bv = bias[col];
#pragma unroll
    for (int m = 0; m < 2; ++m) {
#pragma unroll
      for (int i = 0; i < 4; ++i) {
        const int row = row0 + wm * 32 + m * 16 + fq * 4 + i;
        float v = acc[m][n][i] + bv;
        if (act == 1) {
          float e = __expf(2.0f * v);
          v = 1.0f - 2.0f * fast_rcp(e + 1.0f);
        } else if (act == 2) {
          v = exp2f(C2 * v);
        }
        C[(size_t)row * 512 + col] = v;
      }
    }
  }
}

// ---------------------------------------------------------------------------
// Kek: Ek = exp2(C2 * keys); block 0 reduces Cout = sum(w_att) + b_att.
// ---------------------------------------------------------------------------
__global__ __launch_bounds__(256) void ek_kernel(
    const float* __restrict__ keys, float* __restrict__ Ek,
    const float* __restrict__ w_att, const float* __restrict__ b_att,
    float* __restrict__ Cout)
{
  __shared__ float red[4];
  const int t = threadIdx.x;
  const size_t i4 = (size_t)blockIdx.x * 256 + t;
  float4 v = ((const float4*)keys)[i4];
  float4 o;
  o.x = exp2f(C2 * v.x); o.y = exp2f(C2 * v.y);
  o.z = exp2f(C2 * v.z); o.w = exp2f(C2 * v.w);
  ((float4*)Ek)[i4] = o;

  if (blockIdx.x == 0) {
    float wsum = w_att[t] + w_att[t + 256];
#pragma unroll
    for (int m = 32; m; m >>= 1) wsum += __shfl_xor(wsum, m);
    if ((t & 63) == 0) red[t >> 6] = wsum;
    __syncthreads();
    if (t == 0) Cout[0] = red[0] + red[1] + red[2] + red[3] + b_att[0];
  }
}

// ---------------------------------------------------------------------------
// K2: partial scores over half the n-range (n-split for occupancy).
// grid.z = 32: b = z>>1, half = z&1. half0 adds Cv, half1 adds 0.
// 32x32 (q,k) tile, 2x2 microtile, pairwise-combined rcp.
// ---------------------------------------------------------------------------
__global__ __launch_bounds__(256, 8) void score_kernel(
    const float* __restrict__ Ea, const float* __restrict__ Ek,
    const float* __restrict__ w_att, const float* __restrict__ Cptr,
    float* __restrict__ s0, float* __restrict__ s1)
{
  __shared__ float ea_s[32][68];
  __shared__ float ek_s[32][68];
  __shared__ float w_s[256];

  const int z = blockIdx.z;
  const int b = z >> 1, half = z & 1;
  const int q0 = blockIdx.y * 32, k0 = blockIdx.x * 32;
  const int t = threadIdx.x;
  w_s[t] = w_att[half * 256 + t];

  const int qi = t >> 4, ki = t & 15;
  const int lr = t >> 3, lc = (t & 7) * 8;
  const float* eap = Ea + (size_t)(b * 256 + q0) * 512 + half * 256;
  const float* ekp = Ek + (size_t)(b * 256 + k0) * 512 + half * 256;

  float acc00 = 0.f, acc01 = 0.f, acc10 = 0.f, acc11 = 0.f;

  // w1/q1 + w2/q2 = (w1*q2 + w2*q1) * rcp(q1*q2),  q = fma(Ea,Ek,1)
#define TERM2(ax, ay, kx, ky, wx, wy, accv) { \
    float q1_ = fmaf(ax, kx, 1.0f); \
    float q2_ = fmaf(ay, ky, 1.0f); \
    float N_ = fmaf(wy, q1_, wx * q2_); \
    accv = fmaf(N_, fast_rcp(q1_ * q2_), accv); }

  for (int c = 0; c < 4; ++c) {
    const int gb = lr * 512 + c * 64 + lc;
    float4 A0 = *(const float4*)&eap[gb];
    float4 A1 = *(const float4*)&eap[gb + 4];
    float4 K0 = *(const float4*)&ekp[gb];
    float4 K1 = *(const float4*)&ekp[gb + 4];
    __syncthreads();
    *(float4*)&ea_s[lr][lc] = A0;
    *(float4*)&ea_s[lr][lc + 4] = A1;
    *(float4*)&ek_s[lr][lc] = K0;
    *(float4*)&ek_s[lr][lc + 4] = K1;
    __syncthreads();

#pragma unroll
    for (int j = 0; j < 64; j += 4) {
      float4 a0 = *(const float4*)&ea_s[qi][j];
      float4 a1 = *(const float4*)&ea_s[qi + 16][j];
      float4 k0v = *(const float4*)&ek_s[ki][j];
      float4 k1v = *(const float4*)&ek_s[ki + 16][j];
      float4 wv = *(const float4*)&w_s[c * 64 + j];
      TERM2(a0.x, a0.y, k0v.x, k0v.y, wv.x, wv.y, acc00);
      TERM2(a0.z, a0.w, k0v.z, k0v.w, wv.z, wv.w, acc00);
      TERM2(a0.x, a0.y, k1v.x, k1v.y, wv.x, wv.y, acc01);
      TERM2(a0.z, a0.w, k1v.z, k1v.w, wv.z, wv.w, acc01);
      TERM2(a1.x, a1.y, k0v.x, k0v.y, wv.x, wv.y, acc10);
      TERM2(a1.z, a1.w, k0v.z, k0v.w, wv.z, wv.w, acc10);
      TERM2(a1.x, a1.y, k1v.x, k1v.y, wv.x, wv.y, acc11);
      TERM2(a1.z, a1.w, k1v.z, k1v.w, wv.z, wv.w, acc11);
    }
  }
#undef TERM2

  const float Cv = half ? 0.0f : Cptr[0];
  float* sc = half ? s1 : s0;
  const size_t qr = (size_t)(b * 256 + q0 + qi);
  sc[qr * 256 + k0 + ki]             = fmaf(-2.f, acc00, Cv);
  sc[qr * 256 + k0 + ki + 16]        = fmaf(-2.f, acc01, Cv);
  sc[(qr + 16) * 256 + k0 + ki]      = fmaf(-2.f, acc10, Cv);
  sc[(qr + 16) * 256 + k0 + ki + 16] = fmaf(-2.f, acc11, Cv);
}

// ---------------------------------------------------------------------------
// K3: softmax over k of (s0+s1) (writes p) + ctx = p @ keys[b]
// ---------------------------------------------------------------------------
__global__ __launch_bounds__(256) void softmax_ctx_kernel(
    const float* __restrict__ s0, const float* __restrict__ s1,
    const float* __restrict__ keys,
    float* __restrict__ p_out, float* __restrict__ ctx)
{
  __shared__ float p_s[16][260];
  __shared__ float k_s[16 * 512];

  const int b = blockIdx.y, q0 = blockIdx.x * 16;
  const int t = threadIdx.x;
  const int wv = t >> 6, lane = t & 63;

#pragma unroll
  for (int i = 0; i < 4; ++i) {
    const int r = wv * 4 + i;
    const size_t off = (size_t)(b * 256 + q0 + r) * 256 + lane * 4;
    float4 sa = *(const float4*)&s0[off];
    float4 sb = *(const float4*)&s1[off];
    float4 s4 = {sa.x + sb.x, sa.y + sb.y, sa.z + sb.z, sa.w + sb.w};
    float m = fmaxf(fmaxf(s4.x, s4.y), fmaxf(s4.z, s4.w));
#pragma unroll
    for (int msk = 32; msk; msk >>= 1) m = fmaxf(m, __shfl_xor(m, msk));
    float e0 = __expf(s4.x - m);
    float e1 = __expf(s4.y - m);
    float e2 = __expf(s4.z - m);
    float e3 = __expf(s4.w - m);
    float ssum = (e0 + e1) + (e2 + e3);
#pragma unroll
    for (int msk = 32; msk; msk >>= 1) ssum += __shfl_xor(ssum, msk);
    float rs = 1.0f / ssum;
    float4 p4 = {e0 * rs, e1 * rs, e2 * rs, e3 * rs};
    *(float4*)&p_s[r][lane * 4] = p4;
    *(float4*)&p_out[off] = p4;
  }

  const int qg = t >> 6;
  const int ng = t & 63;
  float acc[4][8] = {};
  for (int kc = 0; kc < 256; kc += 16) {
    __syncthreads();
    const float* kbase = keys + (size_t)(b * 256 + kc) * 512;
#pragma unroll
    for (int u = 0; u < 8; ++u)
      *(float4*)&k_s[u * 1024 + t * 4] = *(const float4*)&kbase[u * 1024 + t * 4];
    __syncthreads();
#pragma unroll 4
    for (int kk = 0; kk < 16; ++kk) {
      float p0 = p_s[qg * 4 + 0][kc + kk];
      float p1 = p_s[qg * 4 + 1][kc + kk];
      float p2 = p_s[qg * 4 + 2][kc + kk];
      float p3 = p_s[qg * 4 + 3][kc + kk];
#pragma unroll
      for (int j = 0; j < 8; ++j) {
        float kv = k_s[kk * 512 + ng + j * 64];
        acc[0][j] = fmaf(p0, kv, acc[0][j]);
        acc[1][j] = fmaf(p1, kv, acc[1][j]);
        acc[2][j] = fmaf(p2, kv, acc[2][j]);
        acc[3][j] = fmaf(p3, kv, acc[3][j]);
      }
    }
  }

  __syncthreads();
#pragma unroll
  for (int i = 0; i < 4; ++i)
#pragma unroll
    for (int j = 0; j < 8; ++j)
      k_s[(qg * 4 + i) * 512 + ng + j * 64] = acc[i][j];
  __syncthreads();
  float* cb = ctx + (size_t)(b * 256 + q0) * 512;
#pragma unroll
  for (int u = 0; u < 8; ++u)
    *(float4*)&cb[u * 1024 + t * 4] = *(const float4*)&k_s[u * 1024 + t * 4];
}

// ---------------------------------------------------------------------------
extern "C" void kernel_launch(void* const* d_in, const int* in_sizes, int n_in,
                              void* d_out, int out_size, void* d_ws, size_t ws_size,
                              hipStream_t stream) {
  const float* query = (const float*)d_in[0];
  const float* keys  = (const float*)d_in[1];
  const float* Wq    = (const float*)d_in[2];
  const float* bq    = (const float*)d_in[3];
  const float* w_att = (const float*)d_in[4];
  const float* b_att = (const float*)d_in[5];
  const float* Wout  = (const float*)d_in[6];
  const float* bout  = (const float*)d_in[7];

  float* out_tanh = (float*)d_out;                  // [4096][512]
  float* out_p    = out_tanh + (size_t)4096 * 512;  // [4096][256]

  float* ws = (float*)d_ws;
  float* Ea     = ws;                    // [4096][512] f32
  float* Ek     = ws + 2097152;          // [4096][512] f32
  float* s0     = ws + 4194304;          // [4096][256] f32
  float* s1     = ws + 5242880;          // [4096][256] f32
  float* Cptr   = ws + 6291456;          // [1] (+pad)
  u16*   Wqt    = (u16*)(ws + 6291472);  // [512][512] bf16
  u16*   Woutt  = Wqt + 262144;          // [512][1024] bf16
  float* ctx    = Ea;                    // alias: Ea dead when K3 writes ctx

  transpose_w_bf16<<<dim3(16, 16), 256, 0, stream>>>(Wq, Wqt, 512);
  transpose_w_bf16<<<dim3(16, 32), 256, 0, stream>>>(Wout, Woutt, 1024);

  ek_kernel<<<2048, 256, 0, stream>>>(keys, Ek, w_att, b_att, Cptr);

  // K1: Ea = exp2(C2 * (query @ Wq + bq))   [MFMA bf16, 64x64 tile]
  gemm_mfma_bf16<<<dim3(8, 64), 256, 0, stream>>>(
      query, query, 512, Wqt, bq, Ea, 512, 2);

  // K2: partial scores (n-split halves)
  score_kernel<<<dim3(8, 8, 32), 256, 0, stream>>>(
      Ea, Ek, w_att, Cptr, s0, s1);

  // K3: softmax of s0+s1 (writes p) + context
  softmax_ctx_kernel<<<dim3(16, 16), 256, 0, stream>>>(
      s0, s1, keys, out_p, ctx);

  // K4: out = tanh(concat(query, ctx) @ Wout + bout)   [MFMA bf16]
  gemm_mfma_bf16<<<dim3(8, 64), 256, 0, stream>>>(
      query, ctx, 512, Woutt, bout, out_tanh, 1024, 1);
}

// Round 5
// 142.326 us; speedup vs baseline: 3.8518x; 3.8518x over previous
//
#include <hip/hip_runtime.h>

// Problem constants: B=16, TQ=256, TK=256, QD=512, KD=512
// d_out = [ tanh_out: 16*256*512 f32 ; p: 16*256*256 f32 ]
// scores[b,q,k] = (sum_n w_n + b_att) - 2 * sum_n w_n / (1 + Ea[q,n]*Ek[k,n])
//   Ea = exp2(C2*aq), Ek = exp2(C2*keys), C2 = 2*log2(e)
// Pairwise: w1/q1 + w2/q2 = (w1*q2 + w2*q1) / (q1*q2),  q = 1 + Ea*Ek

#define C2 2.88539008177792681f

typedef unsigned short u16;
typedef short s16x8 __attribute__((ext_vector_type(8)));
typedef float f32x4 __attribute__((ext_vector_type(4)));

__device__ __forceinline__ float fast_rcp(float x) { return __builtin_amdgcn_rcpf(x); }

__device__ __forceinline__ u16 f2bf(float f) {
  union { float f; unsigned u; } v; v.f = f;
  unsigned r = v.u + 0x7fffu + ((v.u >> 16) & 1u);
  return (u16)(r >> 16);
}
__device__ __forceinline__ unsigned packbf(float a, float b) {
  return (unsigned)f2bf(a) | ((unsigned)f2bf(b) << 16);
}

// ---------------------------------------------------------------------------
// Prep: Wt[n][k] = bf16(W[k][n]);  W is [K][512] f32, Wt is [512][K] bf16.
// ---------------------------------------------------------------------------
__global__ __launch_bounds__(256) void transpose_w_bf16(
    const float* __restrict__ W, u16* __restrict__ Wt, int K)
{
  __shared__ u16 tile[32][40];
  const int t = threadIdx.x;
  const int n0 = blockIdx.x * 32, k0 = blockIdx.y * 32;
  const int r = t >> 3, c = (t & 7) * 4;
  float4 v = *(const float4*)&W[(size_t)(k0 + r) * 512 + n0 + c];
  tile[c + 0][r] = f2bf(v.x); tile[c + 1][r] = f2bf(v.y);
  tile[c + 2][r] = f2bf(v.z); tile[c + 3][r] = f2bf(v.w);
  __syncthreads();
  if (t < 128) {
    const int row = t >> 2, ch = (t & 3) * 8;
    unsigned p0 = (unsigned)tile[row][ch + 0] | ((unsigned)tile[row][ch + 1] << 16);
    unsigned p1 = (unsigned)tile[row][ch + 2] | ((unsigned)tile[row][ch + 3] << 16);
    unsigned p2 = (unsigned)tile[row][ch + 4] | ((unsigned)tile[row][ch + 5] << 16);
    unsigned p3 = (unsigned)tile[row][ch + 6] | ((unsigned)tile[row][ch + 7] << 16);
    *(int4*)&Wt[(size_t)(n0 + row) * K + k0 + ch] = make_int4(p0, p1, p2, p3);
  }
}

// ---------------------------------------------------------------------------
// K1/K4: bf16 MFMA GEMM. C[M][512] = act(A @ W + bias), A fp32 -> bf16 staged.
// Tile 64(M) x 64(N), BK=32, 4 waves (2x2), wave tile 32x32 (2x2 frags).
// ---------------------------------------------------------------------------
__global__ __launch_bounds__(256) void gemm_mfma_bf16(
    const float* __restrict__ A0, const float* __restrict__ A1, int kSplit,
    const u16* __restrict__ Bt, const float* __restrict__ bias,
    float* __restrict__ C, int K, int act)
{
  __shared__ u16 As[64 * 32];  // [row][k]
  __shared__ u16 Bs[64 * 32];  // [col][k]
  const int t = threadIdx.x;
  const int lane = t & 63, wid = t >> 6;
  const int wm = wid >> 1, wn = wid & 1;
  const int col0 = blockIdx.x * 64, row0 = blockIdx.y * 64;

  const int ar = t >> 2, ah = (t & 3) * 8;  // A staging: row, 8-elem chunk
  const int br = t >> 2, bc = (t & 3) * 8;  // B staging: col, 8-elem chunk
  const int fr = lane & 15, fg = (lane >> 4) * 8;

  f32x4 acc[2][2] = {};

  for (int k0 = 0; k0 < K; k0 += 32) {
    const float* Asrc; int kc;
    if (k0 < kSplit) { Asrc = A0; kc = k0; } else { Asrc = A1; kc = k0 - kSplit; }
    const float* ap = &Asrc[(size_t)(row0 + ar) * 512 + kc + ah];
    float4 av0 = *(const float4*)(ap + 0);
    float4 av1 = *(const float4*)(ap + 4);
    int4 bv = *(const int4*)&Bt[(size_t)(col0 + br) * K + k0 + bc];
    __syncthreads();
    {
      unsigned p0 = packbf(av0.x, av0.y), p1 = packbf(av0.z, av0.w);
      unsigned p2 = packbf(av1.x, av1.y), p3 = packbf(av1.z, av1.w);
      *(int4*)&As[ar * 32 + ah] = make_int4(p0, p1, p2, p3);
      *(int4*)&Bs[br * 32 + bc] = bv;
    }
    __syncthreads();

    s16x8 af[2], bf[2];
#pragma unroll
    for (int m = 0; m < 2; ++m)
      af[m] = *(const s16x8*)&As[(wm * 32 + m * 16 + fr) * 32 + fg];
#pragma unroll
    for (int n = 0; n < 2; ++n)
      bf[n] = *(const s16x8*)&Bs[(wn * 32 + n * 16 + fr) * 32 + fg];
#pragma unroll
    for (int m = 0; m < 2; ++m)
#pragma unroll
      for (int n = 0; n < 2; ++n)
        acc[m][n] = __builtin_amdgcn_mfma_f32_16x16x32_bf16(af[m], bf[n], acc[m][n], 0, 0, 0);
  }

  const int fq = lane >> 4;
#pragma unroll
  for (int n = 0; n < 2; ++n) {
    const int col = col0 + wn * 32 + n * 16 + fr;
    const float bv = bias[col];
#pragma unroll
    for (int m = 0; m < 2; ++m) {
#pragma unroll
      for (int i = 0; i < 4; ++i) {
        const int row = row0 + wm * 32 + m * 16 + fq * 4 + i;
        float v = acc[m][n][i] + bv;
        if (act == 1) {
          float e = __expf(2.0f * v);
          v = 1.0f - 2.0f * fast_rcp(e + 1.0f);
        } else if (act == 2) {
          v = exp2f(C2 * v);
        }
        C[(size_t)row * 512 + col] = v;
      }
    }
  }
}

// ---------------------------------------------------------------------------
// Kek: Ek = exp2(C2 * keys); block 0 reduces Cout = sum(w_att) + b_att.
// ---------------------------------------------------------------------------
__global__ __launch_bounds__(256) void ek_kernel(
    const float* __restrict__ keys, float* __restrict__ Ek,
    const float* __restrict__ w_att, const float* __restrict__ b_att,
    float* __restrict__ Cout)
{
  __shared__ float red[4];
  const int t = threadIdx.x;
  const size_t i4 = (size_t)blockIdx.x * 256 + t;
  float4 v = ((const float4*)keys)[i4];
  float4 o;
  o.x = exp2f(C2 * v.x); o.y = exp2f(C2 * v.y);
  o.z = exp2f(C2 * v.z); o.w = exp2f(C2 * v.w);
  ((float4*)Ek)[i4] = o;

  if (blockIdx.x == 0) {
    float wsum = w_att[t] + w_att[t + 256];
#pragma unroll
    for (int m = 32; m; m >>= 1) wsum += __shfl_xor(wsum, m);
    if ((t & 63) == 0) red[t >> 6] = wsum;
    __syncthreads();
    if (t == 0) Cout[0] = red[0] + red[1] + red[2] + red[3] + b_att[0];
  }
}

// ---------------------------------------------------------------------------
// K2: partial scores over half the n-range (n-split for occupancy).
// grid.z = 32: b = z>>1, half = z&1. half0 adds Cv, half1 adds 0.
// 32x32 (q,k) tile, 2x2 microtile, pairwise-combined rcp.
// NOTE: no min-waves launch_bounds — (256,8) forced 32 VGPRs and spilled
// to scratch (R4: WRITE_SIZE 1.4 GB, 6.6x regression). ~48 VGPRs already
// allows 8 waves/SIMD.
// ---------------------------------------------------------------------------
__global__ __launch_bounds__(256) void score_kernel(
    const float* __restrict__ Ea, const float* __restrict__ Ek,
    const float* __restrict__ w_att, const float* __restrict__ Cptr,
    float* __restrict__ s0, float* __restrict__ s1)
{
  __shared__ float ea_s[32][68];
  __shared__ float ek_s[32][68];
  __shared__ float w_s[256];

  const int z = blockIdx.z;
  const int b = z >> 1, half = z & 1;
  const int q0 = blockIdx.y * 32, k0 = blockIdx.x * 32;
  const int t = threadIdx.x;
  w_s[t] = w_att[half * 256 + t];

  const int qi = t >> 4, ki = t & 15;
  const int lr = t >> 3, lc = (t & 7) * 8;
  const float* eap = Ea + (size_t)(b * 256 + q0) * 512 + half * 256;
  const float* ekp = Ek + (size_t)(b * 256 + k0) * 512 + half * 256;

  float acc00 = 0.f, acc01 = 0.f, acc10 = 0.f, acc11 = 0.f;

  // w1/q1 + w2/q2 = (w1*q2 + w2*q1) * rcp(q1*q2),  q = fma(Ea,Ek,1)
#define TERM2(ax, ay, kx, ky, wx, wy, accv) { \
    float q1_ = fmaf(ax, kx, 1.0f); \
    float q2_ = fmaf(ay, ky, 1.0f); \
    float N_ = fmaf(wy, q1_, wx * q2_); \
    accv = fmaf(N_, fast_rcp(q1_ * q2_), accv); }

  for (int c = 0; c < 4; ++c) {
    const int gb = lr * 512 + c * 64 + lc;
    float4 A0 = *(const float4*)&eap[gb];
    float4 A1 = *(const float4*)&eap[gb + 4];
    float4 K0 = *(const float4*)&ekp[gb];
    float4 K1 = *(const float4*)&ekp[gb + 4];
    __syncthreads();
    *(float4*)&ea_s[lr][lc] = A0;
    *(float4*)&ea_s[lr][lc + 4] = A1;
    *(float4*)&ek_s[lr][lc] = K0;
    *(float4*)&ek_s[lr][lc + 4] = K1;
    __syncthreads();

#pragma unroll
    for (int j = 0; j < 64; j += 4) {
      float4 a0 = *(const float4*)&ea_s[qi][j];
      float4 a1 = *(const float4*)&ea_s[qi + 16][j];
      float4 k0v = *(const float4*)&ek_s[ki][j];
      float4 k1v = *(const float4*)&ek_s[ki + 16][j];
      float4 wv = *(const float4*)&w_s[c * 64 + j];
      TERM2(a0.x, a0.y, k0v.x, k0v.y, wv.x, wv.y, acc00);
      TERM2(a0.z, a0.w, k0v.z, k0v.w, wv.z, wv.w, acc00);
      TERM2(a0.x, a0.y, k1v.x, k1v.y, wv.x, wv.y, acc01);
      TERM2(a0.z, a0.w, k1v.z, k1v.w, wv.z, wv.w, acc01);
      TERM2(a1.x, a1.y, k0v.x, k0v.y, wv.x, wv.y, acc10);
      TERM2(a1.z, a1.w, k0v.z, k0v.w, wv.z, wv.w, acc10);
      TERM2(a1.x, a1.y, k1v.x, k1v.y, wv.x, wv.y, acc11);
      TERM2(a1.z, a1.w, k1v.z, k1v.w, wv.z, wv.w, acc11);
    }
  }
#undef TERM2

  const float Cv = half ? 0.0f : Cptr[0];
  float* sc = half ? s1 : s0;
  const size_t qr = (size_t)(b * 256 + q0 + qi);
  sc[qr * 256 + k0 + ki]             = fmaf(-2.f, acc00, Cv);
  sc[qr * 256 + k0 + ki + 16]        = fmaf(-2.f, acc01, Cv);
  sc[(qr + 16) * 256 + k0 + ki]      = fmaf(-2.f, acc10, Cv);
  sc[(qr + 16) * 256 + k0 + ki + 16] = fmaf(-2.f, acc11, Cv);
}

// ---------------------------------------------------------------------------
// K3: softmax over k of (s0+s1) (writes p) + ctx = p @ keys[b]
// ---------------------------------------------------------------------------
__global__ __launch_bounds__(256) void softmax_ctx_kernel(
    const float* __restrict__ s0, const float* __restrict__ s1,
    const float* __restrict__ keys,
    float* __restrict__ p_out, float* __restrict__ ctx)
{
  __shared__ float p_s[16][260];
  __shared__ float k_s[16 * 512];

  const int b = blockIdx.y, q0 = blockIdx.x * 16;
  const int t = threadIdx.x;
  const int wv = t >> 6, lane = t & 63;

#pragma unroll
  for (int i = 0; i < 4; ++i) {
    const int r = wv * 4 + i;
    const size_t off = (size_t)(b * 256 + q0 + r) * 256 + lane * 4;
    float4 sa = *(const float4*)&s0[off];
    float4 sb = *(const float4*)&s1[off];
    float4 s4 = {sa.x + sb.x, sa.y + sb.y, sa.z + sb.z, sa.w + sb.w};
    float m = fmaxf(fmaxf(s4.x, s4.y), fmaxf(s4.z, s4.w));
#pragma unroll
    for (int msk = 32; msk; msk >>= 1) m = fmaxf(m, __shfl_xor(m, msk));
    float e0 = __expf(s4.x - m);
    float e1 = __expf(s4.y - m);
    float e2 = __expf(s4.z - m);
    float e3 = __expf(s4.w - m);
    float ssum = (e0 + e1) + (e2 + e3);
#pragma unroll
    for (int msk = 32; msk; msk >>= 1) ssum += __shfl_xor(ssum, msk);
    float rs = 1.0f / ssum;
    float4 p4 = {e0 * rs, e1 * rs, e2 * rs, e3 * rs};
    *(float4*)&p_s[r][lane * 4] = p4;
    *(float4*)&p_out[off] = p4;
  }

  const int qg = t >> 6;
  const int ng = t & 63;
  float acc[4][8] = {};
  for (int kc = 0; kc < 256; kc += 16) {
    __syncthreads();
    const float* kbase = keys + (size_t)(b * 256 + kc) * 512;
#pragma unroll
    for (int u = 0; u < 8; ++u)
      *(float4*)&k_s[u * 1024 + t * 4] = *(const float4*)&kbase[u * 1024 + t * 4];
    __syncthreads();
#pragma unroll 4
    for (int kk = 0; kk < 16; ++kk) {
      float p0 = p_s[qg * 4 + 0][kc + kk];
      float p1 = p_s[qg * 4 + 1][kc + kk];
      float p2 = p_s[qg * 4 + 2][kc + kk];
      float p3 = p_s[qg * 4 + 3][kc + kk];
#pragma unroll
      for (int j = 0; j < 8; ++j) {
        float kv = k_s[kk * 512 + ng + j * 64];
        acc[0][j] = fmaf(p0, kv, acc[0][j]);
        acc[1][j] = fmaf(p1, kv, acc[1][j]);
        acc[2][j] = fmaf(p2, kv, acc[2][j]);
        acc[3][j] = fmaf(p3, kv, acc[3][j]);
      }
    }
  }

  __syncthreads();
#pragma unroll
  for (int i = 0; i < 4; ++i)
#pragma unroll
    for (int j = 0; j < 8; ++j)
      k_s[(qg * 4 + i) * 512 + ng + j * 64] = acc[i][j];
  __syncthreads();
  float* cb = ctx + (size_t)(b * 256 + q0) * 512;
#pragma unroll
  for (int u = 0; u < 8; ++u)
    *(float4*)&cb[u * 1024 + t * 4] = *(const float4*)&k_s[u * 1024 + t * 4];
}

// ---------------------------------------------------------------------------
extern "C" void kernel_launch(void* const* d_in, const int* in_sizes, int n_in,
                              void* d_out, int out_size, void* d_ws, size_t ws_size,
                              hipStream_t stream) {
  const float* query = (const float*)d_in[0];
  const float* keys  = (const float*)d_in[1];
  const float* Wq    = (const float*)d_in[2];
  const float* bq    = (const float*)d_in[3];
  const float* w_att = (const float*)d_in[4];
  const float* b_att = (const float*)d_in[5];
  const float* Wout  = (const float*)d_in[6];
  const float* bout  = (const float*)d_in[7];

  float* out_tanh = (float*)d_out;                  // [4096][512]
  float* out_p    = out_tanh + (size_t)4096 * 512;  // [4096][256]

  float* ws = (float*)d_ws;
  float* Ea     = ws;                    // [4096][512] f32
  float* Ek     = ws + 2097152;          // [4096][512] f32
  float* s0     = ws + 4194304;          // [4096][256] f32
  float* s1     = ws + 5242880;          // [4096][256] f32
  float* Cptr   = ws + 6291456;          // [1] (+pad)
  u16*   Wqt    = (u16*)(ws + 6291472);  // [512][512] bf16
  u16*   Woutt  = Wqt + 262144;          // [512][1024] bf16
  float* ctx    = Ea;                    // alias: Ea dead when K3 writes ctx

  transpose_w_bf16<<<dim3(16, 16), 256, 0, stream>>>(Wq, Wqt, 512);
  transpose_w_bf16<<<dim3(16, 32), 256, 0, stream>>>(Wout, Woutt, 1024);

  ek_kernel<<<2048, 256, 0, stream>>>(keys, Ek, w_att, b_att, Cptr);

  // K1: Ea = exp2(C2 * (query @ Wq + bq))   [MFMA bf16, 64x64 tile]
  gemm_mfma_bf16<<<dim3(8, 64), 256, 0, stream>>>(
      query, query, 512, Wqt, bq, Ea, 512, 2);

  // K2: partial scores (n-split halves)
  score_kernel<<<dim3(8, 8, 32), 256, 0, stream>>>(
      Ea, Ek, w_att, Cptr, s0, s1);

  // K3: softmax of s0+s1 (writes p) + context
  softmax_ctx_kernel<<<dim3(16, 16), 256, 0, stream>>>(
      s0, s1, keys, out_p, ctx);

  // K4: out = tanh(concat(query, ctx) @ Wout + bout)   [MFMA bf16]
  gemm_mfma_bf16<<<dim3(8, 64), 256, 0, stream>>>(
      query, ctx, 512, Woutt, bout, out_tanh, 1024, 1);
}

// Round 6
// 138.621 us; speedup vs baseline: 3.9548x; 1.0267x over previous
//
#include <hip/hip_runtime.h>

// Problem constants: B=16, TQ=256, TK=256, QD=512, KD=512
// d_out = [ tanh_out: 16*256*512 f32 ; p: 16*256*256 f32 ]
// scores[b,q,k] = (sum_n w_n + b_att) - 2 * sum_n w_n / (1 + Ea[q,n]*Ek[k,n])
//   Ea = exp2(C2*aq), Ek = exp2(C2*keys), C2 = 2*log2(e)
// 4:1 rational combine: sum_{i=1..4} wi/qi = (N12*D34 + N34*D12)/(D12*D34)
//   N12 = w1*q2 + w2*q1, D12 = q1*q2, etc.  One rcp per 4 elements.

#define C2 2.88539008177792681f

typedef unsigned short u16;
typedef short s16x8 __attribute__((ext_vector_type(8)));
typedef float f32x4 __attribute__((ext_vector_type(4)));

__device__ __forceinline__ float fast_rcp(float x) { return __builtin_amdgcn_rcpf(x); }

__device__ __forceinline__ u16 f2bf(float f) {
  union { float f; unsigned u; } v; v.f = f;
  unsigned r = v.u + 0x7fffu + ((v.u >> 16) & 1u);
  return (u16)(r >> 16);
}
__device__ __forceinline__ unsigned packbf(float a, float b) {
  return (unsigned)f2bf(a) | ((unsigned)f2bf(b) << 16);
}

// ---------------------------------------------------------------------------
// Prep: Wt[n][k] = bf16(W[k][n]);  W is [K][512] f32, Wt is [512][K] bf16.
// ---------------------------------------------------------------------------
__global__ __launch_bounds__(256) void transpose_w_bf16(
    const float* __restrict__ W, u16* __restrict__ Wt, int K)
{
  __shared__ u16 tile[32][40];
  const int t = threadIdx.x;
  const int n0 = blockIdx.x * 32, k0 = blockIdx.y * 32;
  const int r = t >> 3, c = (t & 7) * 4;
  float4 v = *(const float4*)&W[(size_t)(k0 + r) * 512 + n0 + c];
  tile[c + 0][r] = f2bf(v.x); tile[c + 1][r] = f2bf(v.y);
  tile[c + 2][r] = f2bf(v.z); tile[c + 3][r] = f2bf(v.w);
  __syncthreads();
  if (t < 128) {
    const int row = t >> 2, ch = (t & 3) * 8;
    unsigned p0 = (unsigned)tile[row][ch + 0] | ((unsigned)tile[row][ch + 1] << 16);
    unsigned p1 = (unsigned)tile[row][ch + 2] | ((unsigned)tile[row][ch + 3] << 16);
    unsigned p2 = (unsigned)tile[row][ch + 4] | ((unsigned)tile[row][ch + 5] << 16);
    unsigned p3 = (unsigned)tile[row][ch + 6] | ((unsigned)tile[row][ch + 7] << 16);
    *(int4*)&Wt[(size_t)(n0 + row) * K + k0 + ch] = make_int4(p0, p1, p2, p3);
  }
}

// ---------------------------------------------------------------------------
// K1/K4: bf16 MFMA GEMM. C[M][512] = act(A @ W + bias), A fp32 -> bf16 staged.
// Tile 64(M) x 64(N), BK=32, 4 waves (2x2), wave tile 32x32 (2x2 frags).
// ---------------------------------------------------------------------------
__global__ __launch_bounds__(256) void gemm_mfma_bf16(
    const float* __restrict__ A0, const float* __restrict__ A1, int kSplit,
    const u16* __restrict__ Bt, const float* __restrict__ bias,
    float* __restrict__ C, int K, int act)
{
  __shared__ u16 As[64 * 32];  // [row][k]
  __shared__ u16 Bs[64 * 32];  // [col][k]
  const int t = threadIdx.x;
  const int lane = t & 63, wid = t >> 6;
  const int wm = wid >> 1, wn = wid & 1;
  const int col0 = blockIdx.x * 64, row0 = blockIdx.y * 64;

  const int ar = t >> 2, ah = (t & 3) * 8;
  const int br = t >> 2, bc = (t & 3) * 8;
  const int fr = lane & 15, fg = (lane >> 4) * 8;

  f32x4 acc[2][2] = {};

  for (int k0 = 0; k0 < K; k0 += 32) {
    const float* Asrc; int kc;
    if (k0 < kSplit) { Asrc = A0; kc = k0; } else { Asrc = A1; kc = k0 - kSplit; }
    const float* ap = &Asrc[(size_t)(row0 + ar) * 512 + kc + ah];
    float4 av0 = *(const float4*)(ap + 0);
    float4 av1 = *(const float4*)(ap + 4);
    int4 bv = *(const int4*)&Bt[(size_t)(col0 + br) * K + k0 + bc];
    __syncthreads();
    {
      unsigned p0 = packbf(av0.x, av0.y), p1 = packbf(av0.z, av0.w);
      unsigned p2 = packbf(av1.x, av1.y), p3 = packbf(av1.z, av1.w);
      *(int4*)&As[ar * 32 + ah] = make_int4(p0, p1, p2, p3);
      *(int4*)&Bs[br * 32 + bc] = bv;
    }
    __syncthreads();

    s16x8 af[2], bf[2];
#pragma unroll
    for (int m = 0; m < 2; ++m)
      af[m] = *(const s16x8*)&As[(wm * 32 + m * 16 + fr) * 32 + fg];
#pragma unroll
    for (int n = 0; n < 2; ++n)
      bf[n] = *(const s16x8*)&Bs[(wn * 32 + n * 16 + fr) * 32 + fg];
#pragma unroll
    for (int m = 0; m < 2; ++m)
#pragma unroll
      for (int n = 0; n < 2; ++n)
        acc[m][n] = __builtin_amdgcn_mfma_f32_16x16x32_bf16(af[m], bf[n], acc[m][n], 0, 0, 0);
  }

  const int fq = lane >> 4;
#pragma unroll
  for (int n = 0; n < 2; ++n) {
    const int col = col0 + wn * 32 + n * 16 + fr;
    const float bv = bias[col];
#pragma unroll
    for (int m = 0; m < 2; ++m) {
#pragma unroll
      for (int i = 0; i < 4; ++i) {
        const int row = row0 + wm * 32 + m * 16 + fq * 4 + i;
        float v = acc[m][n][i] + bv;
        if (act == 1) {
          float e = __expf(2.0f * v);
          v = 1.0f - 2.0f * fast_rcp(e + 1.0f);
        } else if (act == 2) {
          v = exp2f(C2 * v);
        }
        C[(size_t)row * 512 + col] = v;
      }
    }
  }
}

// ---------------------------------------------------------------------------
// Kek: Ek = exp2(C2 * keys); block 0 reduces Cout = sum(w_att) + b_att.
// ---------------------------------------------------------------------------
__global__ __launch_bounds__(256) void ek_kernel(
    const float* __restrict__ keys, float* __restrict__ Ek,
    const float* __restrict__ w_att, const float* __restrict__ b_att,
    float* __restrict__ Cout)
{
  __shared__ float red[4];
  const int t = threadIdx.x;
  const size_t i4 = (size_t)blockIdx.x * 256 + t;
  float4 v = ((const float4*)keys)[i4];
  float4 o;
  o.x = exp2f(C2 * v.x); o.y = exp2f(C2 * v.y);
  o.z = exp2f(C2 * v.z); o.w = exp2f(C2 * v.w);
  ((float4*)Ek)[i4] = o;

  if (blockIdx.x == 0) {
    float wsum = w_att[t] + w_att[t + 256];
#pragma unroll
    for (int m = 32; m; m >>= 1) wsum += __shfl_xor(wsum, m);
    if ((t & 63) == 0) red[t >> 6] = wsum;
    __syncthreads();
    if (t == 0) Cout[0] = red[0] + red[1] + red[2] + red[3] + b_att[0];
  }
}

// ---------------------------------------------------------------------------
// K2: partial scores over half the n-range. grid (4,4,32): b=z>>1, half=z&1.
// 64x64 (q,k) tile, 256 threads, 4x4 microtile, 4:1-combined rcp.
// LDS bytes/elem cut 2.7x vs 32x32/2x2 (R5 was LDS-pipe co-bound: 5 b128
// per 4096 elems -> 9 per 16384). No min-waves bound (R4 spill lesson).
// ---------------------------------------------------------------------------
__global__ __launch_bounds__(256) void score_kernel(
    const float* __restrict__ Ea, const float* __restrict__ Ek,
    const float* __restrict__ w_att, const float* __restrict__ Cptr,
    float* __restrict__ s0, float* __restrict__ s1)
{
  __shared__ float ea_s[64][68];
  __shared__ float ek_s[64][68];
  __shared__ float w_s[256];

  const int z = blockIdx.z;
  const int b = z >> 1, half = z & 1;
  const int q0 = blockIdx.y * 64, k0 = blockIdx.x * 64;
  const int t = threadIdx.x;
  w_s[t] = w_att[half * 256 + t];

  const int qi = t >> 4, ki = t & 15;       // microtile origin
  const int lr = t >> 2, lc = (t & 3) * 16; // staging: row, 16-elem chunk
  const float* eap = Ea + (size_t)(b * 256 + q0) * 512 + half * 256;
  const float* ekp = Ek + (size_t)(b * 256 + k0) * 512 + half * 256;

  float acc[4][4] = {};

  for (int c = 0; c < 4; ++c) {
    const int gb = lr * 512 + c * 64 + lc;
    float4 A0 = *(const float4*)&eap[gb + 0];
    float4 A1 = *(const float4*)&eap[gb + 4];
    float4 A2 = *(const float4*)&eap[gb + 8];
    float4 A3 = *(const float4*)&eap[gb + 12];
    float4 K0 = *(const float4*)&ekp[gb + 0];
    float4 K1 = *(const float4*)&ekp[gb + 4];
    float4 K2 = *(const float4*)&ekp[gb + 8];
    float4 K3 = *(const float4*)&ekp[gb + 12];
    __syncthreads();  // prev chunk consumed (covers w_s init at c=0)
    *(float4*)&ea_s[lr][lc + 0]  = A0;
    *(float4*)&ea_s[lr][lc + 4]  = A1;
    *(float4*)&ea_s[lr][lc + 8]  = A2;
    *(float4*)&ea_s[lr][lc + 12] = A3;
    *(float4*)&ek_s[lr][lc + 0]  = K0;
    *(float4*)&ek_s[lr][lc + 4]  = K1;
    *(float4*)&ek_s[lr][lc + 8]  = K2;
    *(float4*)&ek_s[lr][lc + 12] = K3;
    __syncthreads();

    for (int j = 0; j < 64; j += 4) {
      float4 av[4], kv[4];
#pragma unroll
      for (int m = 0; m < 4; ++m) av[m] = *(const float4*)&ea_s[qi + m * 16][j];
#pragma unroll
      for (int n = 0; n < 4; ++n) kv[n] = *(const float4*)&ek_s[ki + n * 16][j];
      float4 wv = *(const float4*)&w_s[c * 64 + j];
#pragma unroll
      for (int m = 0; m < 4; ++m) {
#pragma unroll
        for (int n = 0; n < 4; ++n) {
          float q1 = fmaf(av[m].x, kv[n].x, 1.0f);
          float q2 = fmaf(av[m].y, kv[n].y, 1.0f);
          float q3 = fmaf(av[m].z, kv[n].z, 1.0f);
          float q4 = fmaf(av[m].w, kv[n].w, 1.0f);
          float N12 = fmaf(wv.x, q2, wv.y * q1);
          float D12 = q1 * q2;
          float N34 = fmaf(wv.z, q4, wv.w * q3);
          float D34 = q3 * q4;
          float Nt = fmaf(N12, D34, N34 * D12);
          float Dt = D12 * D34;
          acc[m][n] = fmaf(Nt, fast_rcp(Dt), acc[m][n]);
        }
      }
    }
  }

  const float Cv = half ? 0.0f : Cptr[0];
  float* sc = half ? s1 : s0;
#pragma unroll
  for (int m = 0; m < 4; ++m) {
    const size_t qr = (size_t)(b * 256 + q0 + qi + m * 16);
#pragma unroll
    for (int n = 0; n < 4; ++n)
      sc[qr * 256 + k0 + ki + n * 16] = fmaf(-2.f, acc[m][n], Cv);
  }
}

// ---------------------------------------------------------------------------
// K3: softmax over k of (s0+s1) (writes p) + ctx = p @ keys[b]
// ---------------------------------------------------------------------------
__global__ __launch_bounds__(256) void softmax_ctx_kernel(
    const float* __restrict__ s0, const float* __restrict__ s1,
    const float* __restrict__ keys,
    float* __restrict__ p_out, float* __restrict__ ctx)
{
  __shared__ float p_s[16][260];
  __shared__ float k_s[16 * 512];

  const int b = blockIdx.y, q0 = blockIdx.x * 16;
  const int t = threadIdx.x;
  const int wv = t >> 6, lane = t & 63;

#pragma unroll
  for (int i = 0; i < 4; ++i) {
    const int r = wv * 4 + i;
    const size_t off = (size_t)(b * 256 + q0 + r) * 256 + lane * 4;
    float4 sa = *(const float4*)&s0[off];
    float4 sb = *(const float4*)&s1[off];
    float4 s4 = {sa.x + sb.x, sa.y + sb.y, sa.z + sb.z, sa.w + sb.w};
    float m = fmaxf(fmaxf(s4.x, s4.y), fmaxf(s4.z, s4.w));
#pragma unroll
    for (int msk = 32; msk; msk >>= 1) m = fmaxf(m, __shfl_xor(m, msk));
    float e0 = __expf(s4.x - m);
    float e1 = __expf(s4.y - m);
    float e2 = __expf(s4.z - m);
    float e3 = __expf(s4.w - m);
    float ssum = (e0 + e1) + (e2 + e3);
#pragma unroll
    for (int msk = 32; msk; msk >>= 1) ssum += __shfl_xor(ssum, msk);
    float rs = 1.0f / ssum;
    float4 p4 = {e0 * rs, e1 * rs, e2 * rs, e3 * rs};
    *(float4*)&p_s[r][lane * 4] = p4;
    *(float4*)&p_out[off] = p4;
  }

  const int qg = t >> 6;
  const int ng = t & 63;
  float acc[4][8] = {};
  for (int kc = 0; kc < 256; kc += 16) {
    __syncthreads();
    const float* kbase = keys + (size_t)(b * 256 + kc) * 512;
#pragma unroll
    for (int u = 0; u < 8; ++u)
      *(float4*)&k_s[u * 1024 + t * 4] = *(const float4*)&kbase[u * 1024 + t * 4];
    __syncthreads();
#pragma unroll 4
    for (int kk = 0; kk < 16; ++kk) {
      float p0 = p_s[qg * 4 + 0][kc + kk];
      float p1 = p_s[qg * 4 + 1][kc + kk];
      float p2 = p_s[qg * 4 + 2][kc + kk];
      float p3 = p_s[qg * 4 + 3][kc + kk];
#pragma unroll
      for (int j = 0; j < 8; ++j) {
        float kv = k_s[kk * 512 + ng + j * 64];
        acc[0][j] = fmaf(p0, kv, acc[0][j]);
        acc[1][j] = fmaf(p1, kv, acc[1][j]);
        acc[2][j] = fmaf(p2, kv, acc[2][j]);
        acc[3][j] = fmaf(p3, kv, acc[3][j]);
      }
    }
  }

  __syncthreads();
#pragma unroll
  for (int i = 0; i < 4; ++i)
#pragma unroll
    for (int j = 0; j < 8; ++j)
      k_s[(qg * 4 + i) * 512 + ng + j * 64] = acc[i][j];
  __syncthreads();
  float* cb = ctx + (size_t)(b * 256 + q0) * 512;
#pragma unroll
  for (int u = 0; u < 8; ++u)
    *(float4*)&cb[u * 1024 + t * 4] = *(const float4*)&k_s[u * 1024 + t * 4];
}

// ---------------------------------------------------------------------------
extern "C" void kernel_launch(void* const* d_in, const int* in_sizes, int n_in,
                              void* d_out, int out_size, void* d_ws, size_t ws_size,
                              hipStream_t stream) {
  const float* query = (const float*)d_in[0];
  const float* keys  = (const float*)d_in[1];
  const float* Wq    = (const float*)d_in[2];
  const float* bq    = (const float*)d_in[3];
  const float* w_att = (const float*)d_in[4];
  const float* b_att = (const float*)d_in[5];
  const float* Wout  = (const float*)d_in[6];
  const float* bout  = (const float*)d_in[7];

  float* out_tanh = (float*)d_out;                  // [4096][512]
  float* out_p    = out_tanh + (size_t)4096 * 512;  // [4096][256]

  float* ws = (float*)d_ws;
  float* Ea     = ws;                    // [4096][512] f32
  float* Ek     = ws + 2097152;          // [4096][512] f32
  float* s0     = ws + 4194304;          // [4096][256] f32
  float* s1     = ws + 5242880;          // [4096][256] f32
  float* Cptr   = ws + 6291456;          // [1] (+pad)
  u16*   Wqt    = (u16*)(ws + 6291472);  // [512][512] bf16
  u16*   Woutt  = Wqt + 262144;          // [512][1024] bf16
  float* ctx    = Ea;                    // alias: Ea dead when K3 writes ctx

  transpose_w_bf16<<<dim3(16, 16), 256, 0, stream>>>(Wq, Wqt, 512);
  transpose_w_bf16<<<dim3(16, 32), 256, 0, stream>>>(Wout, Woutt, 1024);

  ek_kernel<<<2048, 256, 0, stream>>>(keys, Ek, w_att, b_att, Cptr);

  // K1: Ea = exp2(C2 * (query @ Wq + bq))   [MFMA bf16, 64x64 tile]
  gemm_mfma_bf16<<<dim3(8, 64), 256, 0, stream>>>(
      query, query, 512, Wqt, bq, Ea, 512, 2);

  // K2: partial scores (n-split halves), 64x64 tiles
  score_kernel<<<dim3(4, 4, 32), 256, 0, stream>>>(
      Ea, Ek, w_att, Cptr, s0, s1);

  // K3: softmax of s0+s1 (writes p) + context
  softmax_ctx_kernel<<<dim3(16, 16), 256, 0, stream>>>(
      s0, s1, keys, out_p, ctx);

  // K4: out = tanh(concat(query, ctx) @ Wout + bout)   [MFMA bf16]
  gemm_mfma_bf16<<<dim3(8, 64), 256, 0, stream>>>(
      query, ctx, 512, Woutt, bout, out_tanh, 1024, 1);
}